// Round 5
// baseline (201.695 us; speedup 1.0000x reference)
//
#include <hip/hip_runtime.h>

// QueryAndGroup: ball query (first 32 idx within radius, index order, padded
// with first hit) + grouped_xyz (xyz[idx]-center) + grouped feature gather.
// Shapes: xyz (8,16384,3) f32, new_xyz (8,1024,3) f32, features (8,64,16384) f32
// Out: (8, 3+64, 1024, 32) f32.
//
// R10: two-kernel structure (R5-proven); query gets DYNAMIC work stealing.
//  - query: 1024 blocks x 256 (4096 persistent waves, 16 waves/CU). Each wave
//    processes one static query (its global wave id), then grabs more from a
//    device-scope counter. Kills the static-mapping tail (per-CU scan-length
//    variance ~1.6x of balanced time; scans are heavy-tailed 2..32 chunks).
//  - gather: byte-identical to R5 (row-in-LDS, coalesced float4 in/out).
// Budget: ~88us fixed harness fills + kernels. Floor: gather 16.6us
// compulsory HBM + query ~5us balanced. Prediction: 117.6 -> 113-115.

#define BB 8
#define NN 16384
#define SS 1024
#define CC 64
#define NSAMP 32
#define OUTCH (3 + CC)
#define NQ (BB * SS)          // 8192 queries
#define QBLOCKS 1024          // 4096 waves, 16/CU
#define NWAVES (QBLOCKS * 4)

// float(0.04) to match numpy's weak-scalar promotion (NOT 0.2f*0.2f).
#define R2 0.04f

// ---------------- kernel A: ball query (work-stealing) ----------------
__global__ __launch_bounds__(256) void query_kernel(
    const float* __restrict__ xyz,      // (B,N,3)
    const float* __restrict__ new_xyz,  // (B,S,3)
    int* __restrict__ idxq,             // ws: (B*S,32)
    int* __restrict__ qctr,             // ws: 1 int, zeroed
    float* __restrict__ out)            // (B,67,S,32)
{
    __shared__ int sidx[4][NSAMP];

    const int t    = threadIdx.x;
    const int wave = t >> 6;
    const int lane = t & 63;

    int q = blockIdx.x * 4 + wave;      // static first assignment (0..4095)
    while (q < NQ) {
        const int b = q >> 10;
        const int s = q & (SS - 1);

        const float* xb = xyz + (size_t)b * NN * 3;
        const float qx = new_xyz[((size_t)b * SS + s) * 3 + 0];
        const float qy = new_xyz[((size_t)b * SS + s) * 3 + 1];
        const float qz = new_xyz[((size_t)b * SS + s) * 3 + 2];

        int count = 0;
        for (int base = 0; base < NN; base += 512) {
            float d2[8];
            #pragma unroll
            for (int j = 0; j < 8; ++j) {
                const int i = base + j * 64 + lane;
                const float dx = qx - xb[i * 3 + 0];
                const float dy = qy - xb[i * 3 + 1];
                const float dz = qz - xb[i * 3 + 2];
                // numpy order, no FMA contraction
                d2[j] = __fadd_rn(__fadd_rn(__fmul_rn(dx, dx),
                                            __fmul_rn(dy, dy)),
                                  __fmul_rn(dz, dz));
            }
            #pragma unroll
            for (int j = 0; j < 8; ++j) {
                const bool within = d2[j] < R2;
                const unsigned long long m = __ballot(within);
                if (within) {
                    // prefix popcount below lane: v_mbcnt_lo/hi (2 VALU)
                    const int pre = (int)__builtin_amdgcn_mbcnt_hi(
                        (unsigned)(m >> 32),
                        __builtin_amdgcn_mbcnt_lo((unsigned)m, 0u));
                    const int pos = count + pre;
                    if (pos < NSAMP) sidx[wave][pos] = base + j * 64 + lane;
                }
                count += __popcll(m);   // uniform -> s_bcnt1
            }
            if (count >= NSAMP) break;   // wave-uniform
        }
        // sidx[wave][*] is wave-private: DS completion suffices (no barrier;
        // waves fully decoupled for work stealing).
        asm volatile("s_waitcnt lgkmcnt(0)" ::: "memory");
        const int cnt = count < NSAMP ? count : NSAMP;
        const int first = (cnt > 0) ? sidx[wave][0] : 0;
        if (lane < NSAMP && lane >= cnt) sidx[wave][lane] = first;
        asm volatile("s_waitcnt lgkmcnt(0)" ::: "memory");

        if (lane < NSAMP) {
            const int k = lane;
            const int idx = sidx[wave][k];
            idxq[(size_t)q * NSAMP + k] = idx;
            // grouped_xyz -> out channels 0..2 (128B coalesced per channel)
            const float gx = xb[idx * 3 + 0] - qx;
            const float gy = xb[idx * 3 + 1] - qy;
            const float gz = xb[idx * 3 + 2] - qz;
            const size_t o = (((size_t)b * OUTCH + 0) * SS + s) * NSAMP + k;
            out[o + 0 * (size_t)SS * NSAMP] = gx;
            out[o + 1 * (size_t)SS * NSAMP] = gy;
            out[o + 2 * (size_t)SS * NSAMP] = gz;
        }

        // dynamic grab: queries NWAVES..NQ-1 come from the shared counter
        int v = 0;
        if (lane == 0)
            v = __hip_atomic_fetch_add(qctr, 1, __ATOMIC_RELAXED,
                                       __HIP_MEMORY_SCOPE_AGENT);
        v = __builtin_amdgcn_readfirstlane(v);
        q = NWAVES + v;
    }
}

// ---------------- kernel B: row-in-LDS gather (R5-proven body) ----------------
// one block per (b,c): stage feats[b,c,:] (64KB) in LDS, gather via LDS,
// write out[b,3+c,:,:] (128KB) fully coalesced.
__global__ __launch_bounds__(512) void gather_kernel(
    const float* __restrict__ feats,    // (B,C,N)
    const int*   __restrict__ idxq,     // (B*S,32)
    float* __restrict__ out)            // (B,67,S,32)
{
    __shared__ float row[NN];           // 64 KB -> 2 blocks/CU

    const int c = blockIdx.x;           // 0..63
    const int b = blockIdx.y;           // 0..7
    const int t = threadIdx.x;          // 0..511

    // stage the full channel row, coalesced float4 (8 KB per wave-instr)
    const float* fr = feats + ((size_t)b * CC + c) * NN;
    #pragma unroll
    for (int i = 0; i < 8; ++i) {
        const int o = (i * 512 + t) * 4;
        *(float4*)(row + o) = *(const float4*)(fr + o);
    }
    __syncthreads();

    // gather: per iter, 512 threads cover 64 s x 32 k (8 lanes x 4k each)
    const int k4 = (t & 7) * 4;
    const int s0 = t >> 3;              // 0..63
    const int*  ib = idxq + (size_t)b * SS * NSAMP;
    float* ob = out + (((size_t)b * OUTCH + 3 + c) * SS) * NSAMP;
    #pragma unroll
    for (int it = 0; it < 16; ++it) {
        const int s = it * 64 + s0;
        const int4 id = *(const int4*)(ib + (size_t)s * NSAMP + k4);
        float4 v;
        v.x = row[id.x];
        v.y = row[id.y];
        v.z = row[id.z];
        v.w = row[id.w];
        *(float4*)(ob + (size_t)s * NSAMP + k4) = v;
    }
}

// ---------------- fallback: R1 fused kernel (if ws too small) ----------------
__global__ __launch_bounds__(64) void qg_fused(
    const float* __restrict__ xyz, const float* __restrict__ new_xyz,
    const float* __restrict__ feats, float* __restrict__ out)
{
    const int bs   = blockIdx.x;
    const int b    = bs >> 10;
    const int s    = bs & (SS - 1);
    const int lane = threadIdx.x;

    const float* xb = xyz + (size_t)b * NN * 3;
    const float qx = new_xyz[((size_t)b * SS + s) * 3 + 0];
    const float qy = new_xyz[((size_t)b * SS + s) * 3 + 1];
    const float qz = new_xyz[((size_t)b * SS + s) * 3 + 2];

    __shared__ int sidx[NSAMP];
    int count = 0;
    for (int base = 0; base < NN; base += 64) {
        const int i = base + lane;
        const float dx = qx - xb[i * 3 + 0];
        const float dy = qy - xb[i * 3 + 1];
        const float dz = qz - xb[i * 3 + 2];
        const float d2 = __fadd_rn(__fadd_rn(__fmul_rn(dx, dx),
                                             __fmul_rn(dy, dy)),
                                   __fmul_rn(dz, dz));
        const bool within = d2 < R2;
        const unsigned long long m = __ballot(within);
        if (within) {
            const int pos = count + __popcll(m & ((1ull << lane) - 1ull));
            if (pos < NSAMP) sidx[pos] = i;
        }
        count += __popcll(m);
        if (count >= NSAMP) break;
    }
    __syncthreads();
    const int cnt = count < NSAMP ? count : NSAMP;
    const int first = (cnt > 0) ? sidx[0] : 0;
    if (lane < NSAMP && lane >= cnt) sidx[lane] = first;
    __syncthreads();

    const int k    = lane & 31;
    const int half = lane >> 5;
    const int idx  = sidx[k];
    const size_t obase = (((size_t)b * OUTCH + 0) * SS + s) * NSAMP + k;
    if (half == 0) {
        out[obase + 0 * (size_t)SS * NSAMP] = xb[idx * 3 + 0] - qx;
        out[obase + 1 * (size_t)SS * NSAMP] = xb[idx * 3 + 1] - qy;
        out[obase + 2 * (size_t)SS * NSAMP] = xb[idx * 3 + 2] - qz;
    }
    const float* fb = feats + (size_t)b * CC * NN;
    const size_t fo = (((size_t)b * OUTCH + 3) * SS + s) * NSAMP + k;
    for (int cch = half; cch < CC; cch += 2) {
        out[fo + (size_t)cch * SS * NSAMP] = fb[(size_t)cch * NN + idx];
    }
}

extern "C" void kernel_launch(void* const* d_in, const int* in_sizes, int n_in,
                              void* d_out, int out_size, void* d_ws, size_t ws_size,
                              hipStream_t stream) {
    const float* xyz     = (const float*)d_in[0];
    const float* new_xyz = (const float*)d_in[1];
    const float* feats   = (const float*)d_in[2];
    float* out           = (float*)d_out;

    const size_t idx_bytes  = (size_t)BB * SS * NSAMP * sizeof(int);   // 1 MB
    const size_t need_bytes = idx_bytes + sizeof(int);

    if (ws_size >= need_bytes) {
        int* idxq = (int*)d_ws;
        int* qctr = (int*)((char*)d_ws + idx_bytes);
        hipMemsetAsync(qctr, 0, sizeof(int), stream);
        query_kernel<<<QBLOCKS, 256, 0, stream>>>(xyz, new_xyz, idxq, qctr, out);
        gather_kernel<<<dim3(CC, BB), 512, 0, stream>>>(feats, idxq, out);
    } else {
        qg_fused<<<BB * SS, 64, 0, stream>>>(xyz, new_xyz, feats, out);
    }
}

// Round 6
// 115.857 us; speedup vs baseline: 1.7409x; 1.7409x over previous
//
#include <hip/hip_runtime.h>

// QueryAndGroup: ball query (first 32 idx within radius, index order, padded
// with first hit) + grouped_xyz (xyz[idx]-center) + grouped feature gather.
// Shapes: xyz (8,16384,3) f32, new_xyz (8,1024,3) f32, features (8,64,16384) f32
// Out: (8, 3+64, 1024, 32) f32.
//
// R11 = R5 byte-identical restore (best harness-verified: 114.9us).
// Session ledger (what NOT to re-try):
//  - R7 NT-store + global_load_lds + idx reg-prefetch gather: +6us
//  - R8 whole-batch fusion (done[b] spin): +85us (straggler-gated, 43% occ)
//  - R9 mbcnt + wave-decoupled lgkmcnt query: +2.7us (≈ fill noise, not a win)
//  - R10 work-stealing query: +84us (while-loop collapsed regalloc to 28
//    VGPRs -> compiler stopped batching the 24 chunk loads -> serialized
//    load latency at half occupancy)
// Structure: dur = ~88us fixed harness poison fills (2x281MB @ 6.4TB/s,
// always the top-5 dispatches) + ~27us kernels (gather ~17 vs 16.6us
// compulsory HBM floor; query ~5-8us latency-bound scan). Margin < fill
// variance.

#define BB 8
#define NN 16384
#define SS 1024
#define CC 64
#define NSAMP 32
#define OUTCH (3 + CC)

// float(0.04) to match numpy's weak-scalar promotion (NOT 0.2f*0.2f).
#define R2 0.04f

// ---------------- kernel A: ball query ----------------
// 4 waves/block, one query per wave, 512-pt chunks (loads batched ahead of
// the ballot phase -> one latency per chunk).
__global__ __launch_bounds__(256) void query_kernel(
    const float* __restrict__ xyz,      // (B,N,3)
    const float* __restrict__ new_xyz,  // (B,S,3)
    int* __restrict__ idxq,             // ws: (B*S,32)
    float* __restrict__ out)            // (B,67,S,32)
{
    __shared__ int sidx[4][NSAMP];

    const int t    = threadIdx.x;
    const int wave = t >> 6;
    const int lane = t & 63;
    const int q    = blockIdx.x * 4 + wave;   // 0..8191
    const int b    = q >> 10;
    const int s    = q & (SS - 1);

    const float* xb = xyz + (size_t)b * NN * 3;
    const float qx = new_xyz[((size_t)b * SS + s) * 3 + 0];
    const float qy = new_xyz[((size_t)b * SS + s) * 3 + 1];
    const float qz = new_xyz[((size_t)b * SS + s) * 3 + 2];
    const unsigned long long below = (1ull << lane) - 1ull;

    int count = 0;
    for (int base = 0; base < NN; base += 512) {
        float d2[8];
        #pragma unroll
        for (int j = 0; j < 8; ++j) {
            const int i = base + j * 64 + lane;
            const float dx = qx - xb[i * 3 + 0];
            const float dy = qy - xb[i * 3 + 1];
            const float dz = qz - xb[i * 3 + 2];
            // numpy order, no FMA contraction
            d2[j] = __fadd_rn(__fadd_rn(__fmul_rn(dx, dx),
                                        __fmul_rn(dy, dy)),
                              __fmul_rn(dz, dz));
        }
        #pragma unroll
        for (int j = 0; j < 8; ++j) {
            const bool within = d2[j] < R2;
            const unsigned long long m = __ballot(within);
            if (within) {
                const int pos = count + __popcll(m & below);
                if (pos < NSAMP) sidx[wave][pos] = base + j * 64 + lane;
            }
            count += __popcll(m);
        }
        if (count >= NSAMP) break;   // wave-uniform
    }
    __syncthreads();
    const int cnt = count < NSAMP ? count : NSAMP;
    const int first = (cnt > 0) ? sidx[wave][0] : 0;
    if (lane < NSAMP && lane >= cnt) sidx[wave][lane] = first;
    __syncthreads();

    if (lane < NSAMP) {
        const int k = lane;
        const int idx = sidx[wave][k];
        idxq[(size_t)q * NSAMP + k] = idx;
        // grouped_xyz -> out channels 0..2 (128B coalesced per channel)
        const float gx = xb[idx * 3 + 0] - qx;
        const float gy = xb[idx * 3 + 1] - qy;
        const float gz = xb[idx * 3 + 2] - qz;
        const size_t o = (((size_t)b * OUTCH + 0) * SS + s) * NSAMP + k;
        out[o + 0 * (size_t)SS * NSAMP] = gx;
        out[o + 1 * (size_t)SS * NSAMP] = gy;
        out[o + 2 * (size_t)SS * NSAMP] = gz;
    }
}

// ---------------- kernel B: row-in-LDS gather ----------------
// one block per (b,c): stage feats[b,c,:] (64KB) in LDS, gather via LDS,
// write out[b,3+c,:,:] (128KB) fully coalesced.
__global__ __launch_bounds__(512) void gather_kernel(
    const float* __restrict__ feats,    // (B,C,N)
    const int*   __restrict__ idxq,     // (B*S,32)
    float* __restrict__ out)            // (B,67,S,32)
{
    __shared__ float row[NN];           // 64 KB -> 2 blocks/CU

    const int c = blockIdx.x;           // 0..63
    const int b = blockIdx.y;           // 0..7
    const int t = threadIdx.x;          // 0..511

    // stage the full channel row, coalesced float4 (8 KB per wave-instr)
    const float* fr = feats + ((size_t)b * CC + c) * NN;
    #pragma unroll
    for (int i = 0; i < 8; ++i) {
        const int o = (i * 512 + t) * 4;
        *(float4*)(row + o) = *(const float4*)(fr + o);
    }
    __syncthreads();

    // gather: per iter, 512 threads cover 64 s x 32 k (8 lanes x 4k each)
    const int k4 = (t & 7) * 4;
    const int s0 = t >> 3;              // 0..63
    const int*  ib = idxq + (size_t)b * SS * NSAMP;
    float* ob = out + (((size_t)b * OUTCH + 3 + c) * SS) * NSAMP;
    #pragma unroll
    for (int it = 0; it < 16; ++it) {
        const int s = it * 64 + s0;
        const int4 id = *(const int4*)(ib + (size_t)s * NSAMP + k4);
        float4 v;
        v.x = row[id.x];
        v.y = row[id.y];
        v.z = row[id.z];
        v.w = row[id.w];
        *(float4*)(ob + (size_t)s * NSAMP + k4) = v;
    }
}

// ---------------- fallback: R1 fused kernel (if ws too small) ----------------
__global__ __launch_bounds__(64) void qg_fused(
    const float* __restrict__ xyz, const float* __restrict__ new_xyz,
    const float* __restrict__ feats, float* __restrict__ out)
{
    const int bs   = blockIdx.x;
    const int b    = bs >> 10;
    const int s    = bs & (SS - 1);
    const int lane = threadIdx.x;

    const float* xb = xyz + (size_t)b * NN * 3;
    const float qx = new_xyz[((size_t)b * SS + s) * 3 + 0];
    const float qy = new_xyz[((size_t)b * SS + s) * 3 + 1];
    const float qz = new_xyz[((size_t)b * SS + s) * 3 + 2];

    __shared__ int sidx[NSAMP];
    int count = 0;
    for (int base = 0; base < NN; base += 64) {
        const int i = base + lane;
        const float dx = qx - xb[i * 3 + 0];
        const float dy = qy - xb[i * 3 + 1];
        const float dz = qz - xb[i * 3 + 2];
        const float d2 = __fadd_rn(__fadd_rn(__fmul_rn(dx, dx),
                                             __fmul_rn(dy, dy)),
                                   __fmul_rn(dz, dz));
        const bool within = d2 < R2;
        const unsigned long long m = __ballot(within);
        if (within) {
            const int pos = count + __popcll(m & ((1ull << lane) - 1ull));
            if (pos < NSAMP) sidx[pos] = i;
        }
        count += __popcll(m);
        if (count >= NSAMP) break;
    }
    __syncthreads();
    const int cnt = count < NSAMP ? count : NSAMP;
    const int first = (cnt > 0) ? sidx[0] : 0;
    if (lane < NSAMP && lane >= cnt) sidx[lane] = first;
    __syncthreads();

    const int k    = lane & 31;
    const int half = lane >> 5;
    const int idx  = sidx[k];
    const size_t obase = (((size_t)b * OUTCH + 0) * SS + s) * NSAMP + k;
    if (half == 0) {
        out[obase + 0 * (size_t)SS * NSAMP] = xb[idx * 3 + 0] - qx;
        out[obase + 1 * (size_t)SS * NSAMP] = xb[idx * 3 + 1] - qy;
        out[obase + 2 * (size_t)SS * NSAMP] = xb[idx * 3 + 2] - qz;
    }
    const float* fb = feats + (size_t)b * CC * NN;
    const size_t fo = (((size_t)b * OUTCH + 3) * SS + s) * NSAMP + k;
    for (int cch = half; cch < CC; cch += 2) {
        out[fo + (size_t)cch * SS * NSAMP] = fb[(size_t)cch * NN + idx];
    }
}

extern "C" void kernel_launch(void* const* d_in, const int* in_sizes, int n_in,
                              void* d_out, int out_size, void* d_ws, size_t ws_size,
                              hipStream_t stream) {
    const float* xyz     = (const float*)d_in[0];
    const float* new_xyz = (const float*)d_in[1];
    const float* feats   = (const float*)d_in[2];
    float* out           = (float*)d_out;

    const size_t idx_bytes = (size_t)BB * SS * NSAMP * sizeof(int);     // 1 MB

    if (ws_size >= idx_bytes) {
        int* idxq = (int*)d_ws;
        query_kernel<<<2048, 256, 0, stream>>>(xyz, new_xyz, idxq, out);
        gather_kernel<<<dim3(CC, BB), 512, 0, stream>>>(feats, idxq, out);
    } else {
        qg_fused<<<BB * SS, 64, 0, stream>>>(xyz, new_xyz, feats, out);
    }
}